// Round 4
// baseline (1560.647 us; speedup 1.0000x reference)
//
#include <hip/hip_runtime.h>

// Problem constants: WIDTH=64 -> S=4096, E=128, B=8, 512 edges/batch.
#define WIDTH 64
#define S 4096
#define E 128
#define BATCH 8
#define EDGES_PER_B 512
#define TOTAL_EDGES (BATCH * EDGES_PER_B)

#define ATTN_FLOATS (BATCH * S * E)     // 4,194,304 floats (16.78 MB)
#define ATTN_N4 (ATTN_FLOATS / 4)       // 1,048,576 float4s

#define GATHER_BLOCKS 256               // 32 blocks per batch
#define SLOTS (TOTAL_EDGES / GATHER_BLOCKS)   // 16 edges per block

typedef float vfloat4 __attribute__((ext_vector_type(4)));

// attn[b,s,e] = bp[e] over the whole region (rows with edges get
// overwritten by gather_kernel afterwards — stream order serializes).
__global__ __launch_bounds__(256) void init_attn_kernel(
    float* __restrict__ attn, const float* __restrict__ bp) {
    const int i = blockIdx.x * 256 + threadIdx.x;   // grid covers ATTN_N4
    reinterpret_cast<vfloat4*>(attn)[i] =
        reinterpret_cast<const vfloat4*>(bp)[i & (E / 4 - 1)];
}

// Per edge: pairflag = first occurrence of (src,dst) in batch (set-once
// semantics); leader = first occurrence of src in batch (row owner).
__global__ void dedupe_kernel(const int* __restrict__ edges,
                              int* __restrict__ pairflag,
                              int* __restrict__ leader) {
    const int b = blockIdx.x;
    __shared__ int keys[EDGES_PER_B];
    __shared__ int srcs[EDGES_PER_B];
    const int4* eb = reinterpret_cast<const int4*>(edges) + b * EDGES_PER_B;
    for (int i = threadIdx.x; i < EDGES_PER_B; i += blockDim.x) {
        int4 e = eb[i];                 // [x0, y0, x1, y1]
        int src = e.y * WIDTH + e.x;    // node = y*WIDTH + x
        int dst = e.w * WIDTH + e.z;
        srcs[i] = src;
        keys[i] = src * S + dst;
    }
    __syncthreads();
    for (int i = threadIdx.x; i < EDGES_PER_B; i += blockDim.x) {
        int k = keys[i], s = srcs[i];
        int uq = 1, ld = 1;
        for (int j = 0; j < i; ++j) {
            if (keys[j] == k) uq = 0;
            if (srcs[j] == s) ld = 0;
        }
        pairflag[b * EDGES_PER_B + i] = uq;
        leader[b * EDGES_PER_B + i] = ld;
    }
}

// Row-gather: one leader block-slot per unique (b,src) row.
//   attn[b,src,:] = ((sum_uniq_dst values[b,dst,:]) @ Wv + cnt*bv) @ Wp + bp
// Weights staged ONCE per block in LDS (Wv for phase 1, Wp for phase 2):
// 256 blocks x 128 KB = 32 MB weight traffic vs 512 MB before. No atomics:
// each output row has exactly one owner; plain 512 B contiguous store.
__global__ __launch_bounds__(128) void gather_kernel(
    const int* __restrict__ edges, const int* __restrict__ pairflag,
    const int* __restrict__ leader, const float* __restrict__ values,
    const float* __restrict__ Wv, const float* __restrict__ bv,
    const float* __restrict__ Wp, const float* __restrict__ bp,
    float* __restrict__ attn) {
    __shared__ float Wl[E * E];          // 64 KB: Wv then Wp
    __shared__ float hv_all[SLOTS][E];   // 8 KB
    __shared__ float vsum[E];
    __shared__ float bvs[E];
    __shared__ float bps[E];
    __shared__ int s_src[EDGES_PER_B];
    __shared__ int s_dst[EDGES_PER_B];
    __shared__ int s_flag[EDGES_PER_B];
    __shared__ int slot_src[SLOTS];

    const int t = threadIdx.x;           // 0..127
    const int blk = blockIdx.x;
    const int b = blk / (GATHER_BLOCKS / BATCH);       // 32 blocks/batch
    const int e0 = blk * SLOTS;                        // global edge base
    const int ib0 = e0 & (EDGES_PER_B - 1);            // in-batch base

    // Stage this batch's edges + flags + biases.
    const int4* eb = reinterpret_cast<const int4*>(edges) + b * EDGES_PER_B;
    for (int i = t; i < EDGES_PER_B; i += 128) {
        int4 e = eb[i];
        s_src[i] = e.y * WIDTH + e.x;
        s_dst[i] = e.w * WIDTH + e.z;
        s_flag[i] = pairflag[b * EDGES_PER_B + i];
    }
    bvs[t] = bv[t];
    bps[t] = bp[t];
    // Stage Wv (64 KB, coalesced float4).
    for (int i = t; i < E * E / 4; i += 128)
        reinterpret_cast<vfloat4*>(Wl)[i] =
            reinterpret_cast<const vfloat4*>(Wv)[i];
    __syncthreads();

    // Phase 1: per leader slot, gather vsum over unique dsts, matvec by Wv.
    for (int s = 0; s < SLOTS; ++s) {
        const int gi = e0 + s;
        if (t == 0) slot_src[s] = -1;
        if (!leader[gi]) continue;       // uniform scalar read -> no diverge
        const int src = s_src[ib0 + s];
        if (t == 0) slot_src[s] = src;
        float vs = 0.0f, fcnt = 0.0f;
        for (int j = 0; j < EDGES_PER_B; ++j) {
            if (s_src[j] == src && s_flag[j]) {   // uniform condition
                vs += values[((size_t)(b * S + s_dst[j])) * E + t];
                fcnt += 1.0f;
            }
        }
        vsum[t] = vs;
        __syncthreads();
        float acc = fcnt * bvs[t];
#pragma unroll 8
        for (int k = 0; k < E; ++k) acc += vsum[k] * Wl[k * E + t];
        hv_all[s][t] = acc;
        __syncthreads();                 // vsum reused next slot
    }
    __syncthreads();

    // Re-stage Wp over the same LDS.
    for (int i = t; i < E * E / 4; i += 128)
        reinterpret_cast<vfloat4*>(Wl)[i] =
            reinterpret_cast<const vfloat4*>(Wp)[i];
    __syncthreads();

    // Phase 2: project by Wp, add bp, one contiguous row store per slot.
    for (int s = 0; s < SLOTS; ++s) {
        const int src = slot_src[s];
        if (src < 0) continue;
        float p = bps[t];
#pragma unroll 8
        for (int k = 0; k < E; ++k) p += hv_all[s][k] * Wl[k * E + t];
        attn[((size_t)(b * S + src)) * E + t] = p;
    }
}

// A1/A2 entries: duplicates write 1.0 to the same address (idempotent).
__global__ __launch_bounds__(256) void ones_kernel(
    const int* __restrict__ edges, float* __restrict__ A1,
    float* __restrict__ A2) {
    const int g = blockIdx.x * 256 + threadIdx.x;   // 0..TOTAL_EDGES-1
    int4 e = reinterpret_cast<const int4*>(edges)[g];
    const int b = g >> 9;
    const int aidx = (b * S + e.y * WIDTH + e.x) * S + (e.w * WIDTH + e.z);
    A1[aidx] = 1.0f;
    A2[aidx] = 1.0f;
}

// -------- fallback (R0 path) if workspace < 32 KB --------
__global__ void scatter_kernel(const int* __restrict__ edges,
                               const int* __restrict__ flags,
                               const float* __restrict__ values,
                               const float* __restrict__ Wv,
                               const float* __restrict__ bv,
                               const float* __restrict__ Wp,
                               float* __restrict__ attn,
                               float* __restrict__ A1,
                               float* __restrict__ A2) {
    const int g = blockIdx.x;
    const int b = g >> 9;
    int4 e = reinterpret_cast<const int4*>(edges)[g];
    const int src = e.y * WIDTH + e.x;
    const int dst = e.w * WIDTH + e.z;
    const int aidx = (b * S + src) * S + dst;
    if (threadIdx.x == 0) A1[aidx] = 1.0f;
    if (threadIdx.x == 1) A2[aidx] = 1.0f;
    if (!flags[g]) return;
    __shared__ float sv[E];
    __shared__ float hv[E];
    const int t = threadIdx.x;
    sv[t] = values[(b * S + dst) * E + t];
    __syncthreads();
    float acc = bv[t];
#pragma unroll 8
    for (int k = 0; k < E; ++k) acc += sv[k] * Wv[k * E + t];
    hv[t] = acc;
    __syncthreads();
    float p = 0.0f;
#pragma unroll 8
    for (int k = 0; k < E; ++k) p += hv[k] * Wp[k * E + t];
    atomicAdd(&attn[(b * S + src) * E + t], p);
}

__global__ void dedupe_only_kernel(const int* __restrict__ edges,
                                   int* __restrict__ flags) {
    const int b = blockIdx.x;
    __shared__ int keys[EDGES_PER_B];
    const int4* eb = reinterpret_cast<const int4*>(edges) + b * EDGES_PER_B;
    for (int i = threadIdx.x; i < EDGES_PER_B; i += blockDim.x) {
        int4 e = eb[i];
        keys[i] = (e.y * WIDTH + e.x) * S + (e.w * WIDTH + e.z);
    }
    __syncthreads();
    for (int i = threadIdx.x; i < EDGES_PER_B; i += blockDim.x) {
        int k = keys[i], uq = 1;
        for (int j = 0; j < i; ++j)
            if (keys[j] == k) { uq = 0; break; }
        flags[b * EDGES_PER_B + i] = uq;
    }
}

extern "C" void kernel_launch(void* const* d_in, const int* in_sizes, int n_in,
                              void* d_out, int out_size, void* d_ws,
                              size_t ws_size, hipStream_t stream) {
    // 0 queries, 1 keys, 2 values, 3 oracle_edges, 4 Wq, 5 bq, 6 Wk, 7 bk,
    // 8 Wv, 9 bv, 10 Wp, 11 bp
    const float* values = (const float*)d_in[2];
    const int*   edges  = (const int*)d_in[3];
    const float* Wv     = (const float*)d_in[8];
    const float* bv     = (const float*)d_in[9];
    const float* Wp     = (const float*)d_in[10];
    const float* bp     = (const float*)d_in[11];

    float* out  = (float*)d_out;
    float* attn = out;                                  // [B,S,E]
    float* A1   = out + (size_t)BATCH * S * E;          // [B,S,S]
    float* A2   = A1 + (size_t)BATCH * S * S;           // [B,S,S]

    // A-region zeroing: rocclr fill sits on the uncached-output write floor
    // (~690 us, 4x-amplified). Keep it.
    (void)hipMemsetAsync(A1, 0, (size_t)2 * BATCH * S * S * sizeof(float),
                         stream);

    init_attn_kernel<<<ATTN_N4 / 256, 256, 0, stream>>>(attn, bp);

    if (ws_size >= (size_t)2 * TOTAL_EDGES * sizeof(int)) {
        int* pairflag = (int*)d_ws;                     // 16 KB
        int* leader   = pairflag + TOTAL_EDGES;         // 16 KB
        dedupe_kernel<<<BATCH, 256, 0, stream>>>(edges, pairflag, leader);
        gather_kernel<<<GATHER_BLOCKS, 128, 0, stream>>>(
            edges, pairflag, leader, values, Wv, bv, Wp, bp, attn);
        ones_kernel<<<TOTAL_EDGES / 256, 256, 0, stream>>>(edges, A1, A2);
    } else {
        int* flags = (int*)d_ws;                        // 16 KB
        dedupe_only_kernel<<<BATCH, 256, 0, stream>>>(edges, flags);
        scatter_kernel<<<TOTAL_EDGES, 128, 0, stream>>>(
            edges, flags, values, Wv, bv, Wp, attn, A1, A2);
    }
}

// Round 5
// 1122.480 us; speedup vs baseline: 1.3904x; 1.3904x over previous
//
#include <hip/hip_runtime.h>

// Problem constants: WIDTH=64 -> S=4096, E=128, B=8, 512 edges/batch.
#define WIDTH 64
#define S 4096
#define E 128
#define BATCH 8
#define EDGES_PER_B 512
#define TOTAL_EDGES (BATCH * EDGES_PER_B)

#define ATTN_FLOATS (BATCH * S * E)     // 4,194,304 floats (16.78 MB)
#define ATTN_N4 (ATTN_FLOATS / 4)       // 1,048,576 float4s

typedef float vfloat4 __attribute__((ext_vector_type(4)));

// attn[b,s,e] = bp[e] everywhere; leader blocks overwrite their rows later
// (separate kernel -> stream order guarantees visibility).
__global__ __launch_bounds__(256) void init_attn_kernel(
    float* __restrict__ attn, const float* __restrict__ bp) {
    const int i = blockIdx.x * 256 + threadIdx.x;   // grid covers ATTN_N4
    reinterpret_cast<vfloat4*>(attn)[i] =
        reinterpret_cast<const vfloat4*>(bp)[i & (E / 4 - 1)];
}

// Per edge: pairflag = first occurrence of (src,dst) in batch (set-once
// semantics); leader = first occurrence of src in batch (row owner).
__global__ void dedupe_kernel(const int* __restrict__ edges,
                              int* __restrict__ pairflag,
                              int* __restrict__ leader) {
    const int b = blockIdx.x;
    __shared__ int keys[EDGES_PER_B];
    __shared__ int srcs[EDGES_PER_B];
    const int4* eb = reinterpret_cast<const int4*>(edges) + b * EDGES_PER_B;
    for (int i = threadIdx.x; i < EDGES_PER_B; i += blockDim.x) {
        int4 e = eb[i];                 // [x0, y0, x1, y1]
        int src = e.y * WIDTH + e.x;    // node = y*WIDTH + x
        int dst = e.w * WIDTH + e.z;
        srcs[i] = src;
        keys[i] = src * S + dst;
    }
    __syncthreads();
    for (int i = threadIdx.x; i < EDGES_PER_B; i += blockDim.x) {
        int k = keys[i], s = srcs[i];
        int uq = 1, ld = 1;
        for (int j = 0; j < i; ++j) {
            if (keys[j] == k) uq = 0;
            if (srcs[j] == s) ld = 0;
        }
        pairflag[b * EDGES_PER_B + i] = uq;
        leader[b * EDGES_PER_B + i] = ld;
    }
}

// One block (128 threads) per edge — R0's parallel shape, ZERO atomics:
//  - every block writes its A1/A2 ones (duplicate pairs: same addr, same
//    value, benign race)
//  - leader blocks own their (b,src) row outright: sum unique-dst values
//    rows, two matvecs, one plain 512 B contiguous store to attn.
__global__ __launch_bounds__(128) void scatter2_kernel(
    const int* __restrict__ edges, const int* __restrict__ pairflag,
    const int* __restrict__ leader, const float* __restrict__ values,
    const float* __restrict__ Wv, const float* __restrict__ bv,
    const float* __restrict__ Wp, const float* __restrict__ bp,
    float* __restrict__ attn, float* __restrict__ A1,
    float* __restrict__ A2) {
    const int g = blockIdx.x;           // edge index, 0..4095
    const int b = g >> 9;               // / EDGES_PER_B
    const int4 e = reinterpret_cast<const int4*>(edges)[g];
    const int src = e.y * WIDTH + e.x;
    const int dst = e.w * WIDTH + e.z;
    const int aidx = (b * S + src) * S + dst;
    if (threadIdx.x == 0) A1[aidx] = 1.0f;
    if (threadIdx.x == 1) A2[aidx] = 1.0f;
    if (!leader[g]) return;             // block-uniform

    // Stage this batch's edge list + pair flags (8 KB LDS, coalesced).
    __shared__ int s_src[EDGES_PER_B];
    __shared__ int s_dst[EDGES_PER_B];
    __shared__ int s_flag[EDGES_PER_B];
    __shared__ float vsum[E];
    __shared__ float hv[E];
    const int t = threadIdx.x;
    const int4* eb = reinterpret_cast<const int4*>(edges) + b * EDGES_PER_B;
    for (int i = t; i < EDGES_PER_B; i += 128) {
        int4 ee = eb[i];
        s_src[i] = ee.y * WIDTH + ee.x;
        s_dst[i] = ee.w * WIDTH + ee.z;
        s_flag[i] = pairflag[b * EDGES_PER_B + i];
    }
    __syncthreads();

    // Gather: sum values rows over this src's unique dsts (group size ~1-4).
    float vs = 0.0f, fcnt = 0.0f;
    for (int j = 0; j < EDGES_PER_B; ++j) {
        if (s_src[j] == src && s_flag[j]) {     // uniform condition
            vs += values[(size_t)(b * S + s_dst[j]) * E + t];
            fcnt += 1.0f;
        }
    }
    vsum[t] = vs;
    __syncthreads();

    // hv = vsum @ Wv + cnt*bv  (reference: v = values@Wv + bv, summed
    // over cnt unique dsts -> bias scales by cnt).
    float acc = fcnt * bv[t];
#pragma unroll 8
    for (int k = 0; k < E; ++k) acc += vsum[k] * Wv[k * E + t];
    hv[t] = acc;
    __syncthreads();

    // attn row = hv @ Wp + bp, single contiguous store.
    float p = bp[t];
#pragma unroll 8
    for (int k = 0; k < E; ++k) p += hv[k] * Wp[k * E + t];
    attn[(size_t)(b * S + src) * E + t] = p;
}

// -------- fallback (R0 path) if workspace < 32 KB --------
__global__ void dedupe_only_kernel(const int* __restrict__ edges,
                                   int* __restrict__ flags) {
    const int b = blockIdx.x;
    __shared__ int keys[EDGES_PER_B];
    const int4* eb = reinterpret_cast<const int4*>(edges) + b * EDGES_PER_B;
    for (int i = threadIdx.x; i < EDGES_PER_B; i += blockDim.x) {
        int4 e = eb[i];
        keys[i] = (e.y * WIDTH + e.x) * S + (e.w * WIDTH + e.z);
    }
    __syncthreads();
    for (int i = threadIdx.x; i < EDGES_PER_B; i += blockDim.x) {
        int k = keys[i], uq = 1;
        for (int j = 0; j < i; ++j)
            if (keys[j] == k) { uq = 0; break; }
        flags[b * EDGES_PER_B + i] = uq;
    }
}

__global__ void scatter_kernel(const int* __restrict__ edges,
                               const int* __restrict__ flags,
                               const float* __restrict__ values,
                               const float* __restrict__ Wv,
                               const float* __restrict__ bv,
                               const float* __restrict__ Wp,
                               float* __restrict__ attn,
                               float* __restrict__ A1,
                               float* __restrict__ A2) {
    const int g = blockIdx.x;
    const int b = g >> 9;
    int4 e = reinterpret_cast<const int4*>(edges)[g];
    const int src = e.y * WIDTH + e.x;
    const int dst = e.w * WIDTH + e.z;
    const int aidx = (b * S + src) * S + dst;
    if (threadIdx.x == 0) A1[aidx] = 1.0f;
    if (threadIdx.x == 1) A2[aidx] = 1.0f;
    if (!flags[g]) return;
    __shared__ float sv[E];
    __shared__ float hv[E];
    const int t = threadIdx.x;
    sv[t] = values[(b * S + dst) * E + t];
    __syncthreads();
    float acc = bv[t];
#pragma unroll 8
    for (int k = 0; k < E; ++k) acc += sv[k] * Wv[k * E + t];
    hv[t] = acc;
    __syncthreads();
    float p = 0.0f;
#pragma unroll 8
    for (int k = 0; k < E; ++k) p += hv[k] * Wp[k * E + t];
    atomicAdd(&attn[(b * S + src) * E + t], p);
}

extern "C" void kernel_launch(void* const* d_in, const int* in_sizes, int n_in,
                              void* d_out, int out_size, void* d_ws,
                              size_t ws_size, hipStream_t stream) {
    // 0 queries, 1 keys, 2 values, 3 oracle_edges, 4 Wq, 5 bq, 6 Wk, 7 bk,
    // 8 Wv, 9 bv, 10 Wp, 11 bp
    const float* values = (const float*)d_in[2];
    const int*   edges  = (const int*)d_in[3];
    const float* Wv     = (const float*)d_in[8];
    const float* bv     = (const float*)d_in[9];
    const float* Wp     = (const float*)d_in[10];
    const float* bp     = (const float*)d_in[11];

    float* out  = (float*)d_out;
    float* attn = out;                                  // [B,S,E]
    float* A1   = out + (size_t)BATCH * S * E;          // [B,S,S]
    float* A2   = A1 + (size_t)BATCH * S * S;           // [B,S,S]

    // A-region zeroing: rocclr fill sits on the uncached-output write floor
    // (~690 us for 4x-amplified 1.073 GB; our custom fills were no faster).
    (void)hipMemsetAsync(A1, 0, (size_t)2 * BATCH * S * S * sizeof(float),
                         stream);

    init_attn_kernel<<<ATTN_N4 / 256, 256, 0, stream>>>(attn, bp);

    if (ws_size >= (size_t)2 * TOTAL_EDGES * sizeof(int)) {  // 32 KB (R4-proven)
        int* pairflag = (int*)d_ws;
        int* leader   = pairflag + TOTAL_EDGES;
        dedupe_kernel<<<BATCH, 256, 0, stream>>>(edges, pairflag, leader);
        scatter2_kernel<<<TOTAL_EDGES, 128, 0, stream>>>(
            edges, pairflag, leader, values, Wv, bv, Wp, bp, attn, A1, A2);
    } else {
        int* flags = (int*)d_ws;
        dedupe_only_kernel<<<BATCH, 256, 0, stream>>>(edges, flags);
        scatter_kernel<<<TOTAL_EDGES, 128, 0, stream>>>(
            edges, flags, values, Wv, bv, Wp, attn, A1, A2);
    }
}

// Round 6
// 1081.907 us; speedup vs baseline: 1.4425x; 1.0375x over previous
//
#include <hip/hip_runtime.h>

// Problem constants: WIDTH=64 -> S=4096, E=128, B=8, 512 edges/batch.
#define WIDTH 64
#define S 4096
#define E 128
#define BATCH 8
#define EDGES_PER_B 512
#define TOTAL_EDGES (BATCH * EDGES_PER_B)

#define ATTN_FLOATS (BATCH * S * E)     // 4,194,304 floats (16.78 MB)
#define ATTN_N4 (ATTN_FLOATS / 4)       // 1,048,576 float4s

typedef float vfloat4 __attribute__((ext_vector_type(4)));

// Session ledger (R0-R5): timed window = harness ws-poison (~690 us, the
// 4.36 GB fillBufferAligned in top-5) + out-poison (~173 us) + our work.
// Our irreducible piece: A1+A2 zeroing (1.073 GB ~ 170 us, rocclr memset
// is at the floor). Everything else must stay < ~30 us.

// attn[b,s,e] = bp[e] everywhere; leader blocks in scatter3 overwrite
// their rows afterwards (separate kernel -> stream order serializes).
__global__ __launch_bounds__(256) void init_attn_kernel(
    float* __restrict__ attn, const float* __restrict__ bp) {
    const int i = blockIdx.x * 256 + threadIdx.x;   // grid covers ATTN_N4
    reinterpret_cast<vfloat4*>(attn)[i] =
        reinterpret_cast<const vfloat4*>(bp)[i & (E / 4 - 1)];
}

// One block (128 threads) per edge. Fully self-contained (no dedupe
// pre-pass): every block writes its A ones; the block whose edge is the
// FIRST occurrence of its src in the batch (leader) owns the output row:
//   attn[b,src,:] = ((sum over unique dsts of values[b,dst,:]) @ Wv
//                    + cnt*bv) @ Wp + bp
// All scans are parallelized across the block (each thread checks 4 of
// the 512 edges); the in-group pair-dedupe runs on the compacted group
// (typical size 1-8), order-independent via original-index compare.
// R5's version ran the 512-iter scan redundantly on all 128 threads of
// ~3850 leader blocks (~40-80 us of VALU) — that is what this removes.
__global__ __launch_bounds__(128) void scatter3_kernel(
    const int* __restrict__ edges, const float* __restrict__ values,
    const float* __restrict__ Wv, const float* __restrict__ bv,
    const float* __restrict__ Wp, const float* __restrict__ bp,
    float* __restrict__ attn, float* __restrict__ A1,
    float* __restrict__ A2) {
    const int g = blockIdx.x;            // edge index, 0..4095
    const int b = g >> 9;                // / EDGES_PER_B
    const int ib = g & (EDGES_PER_B - 1);
    const int4 e = reinterpret_cast<const int4*>(edges)[g];
    const int src = e.y * WIDTH + e.x;   // node = y*WIDTH + x
    const int dst = e.w * WIDTH + e.z;
    const int aidx = (b * S + src) * S + dst;
    // Duplicate pairs: same addr, same value -> benign race.
    if (threadIdx.x == 0) A1[aidx] = 1.0f;
    if (threadIdx.x == 1) A2[aidx] = 1.0f;

    __shared__ int s_src[EDGES_PER_B];
    __shared__ int s_dst[EDGES_PER_B];
    __shared__ int gidx[EDGES_PER_B];    // compacted same-src edge indices
    __shared__ int nl;                   // not-leader flag
    __shared__ int gcnt;
    __shared__ float vsum[E];
    __shared__ float hv[E];
    const int t = threadIdx.x;
    if (t == 0) { nl = 0; gcnt = 0; }
    const int4* eb = reinterpret_cast<const int4*>(edges) + b * EDGES_PER_B;
#pragma unroll
    for (int r = 0; r < EDGES_PER_B / 128; ++r) {
        const int i = t + r * 128;
        int4 ee = eb[i];                 // 65 KB total -> L2-hot
        s_src[i] = ee.y * WIDTH + ee.x;
        s_dst[i] = ee.w * WIDTH + ee.z;
    }
    __syncthreads();

    // Parallel leader test + group collection: 4 edges per thread.
#pragma unroll
    for (int r = 0; r < EDGES_PER_B / 128; ++r) {
        const int j = t + r * 128;
        if (s_src[j] == src) {
            if (j < ib) nl = 1;          // earlier same-src edge exists
            gidx[atomicAdd(&gcnt, 1)] = j;   // LDS atomic, unordered
        }
    }
    __syncthreads();
    if (nl) return;                      // uniform (LDS value post-sync)

    // Gather unique-dst values rows (group size gsz is uniform; typically
    // 1-8). Pair-unique(m): no group member with smaller original index
    // and the same dst.
    const int gsz = gcnt;
    float vs = 0.0f, fcnt = 0.0f;
    for (int m = 0; m < gsz; ++m) {
        const int jm = gidx[m];
        const int dm = s_dst[jm];
        bool uq = true;
        for (int mm = 0; mm < gsz; ++mm) {
            const int jmm = gidx[mm];
            if (jmm < jm && s_dst[jmm] == dm) uq = false;
        }
        if (uq) {
            vs += values[(size_t)(b * S + dm) * E + t];
            fcnt += 1.0f;
        }
    }
    vsum[t] = vs;
    __syncthreads();

    // hv = vsum @ Wv + cnt*bv (bias scales by unique-dst count).
    float acc = fcnt * bv[t];
#pragma unroll 8
    for (int k = 0; k < E; ++k) acc += vsum[k] * Wv[k * E + t];
    hv[t] = acc;
    __syncthreads();

    // attn row = hv @ Wp + bp, one contiguous 512 B store.
    float p = bp[t];
#pragma unroll 8
    for (int k = 0; k < E; ++k) p += hv[k] * Wp[k * E + t];
    attn[(size_t)(b * S + src) * E + t] = p;
}

extern "C" void kernel_launch(void* const* d_in, const int* in_sizes, int n_in,
                              void* d_out, int out_size, void* d_ws,
                              size_t ws_size, hipStream_t stream) {
    // 0 queries, 1 keys, 2 values, 3 oracle_edges, 4 Wq, 5 bq, 6 Wk, 7 bk,
    // 8 Wv, 9 bv, 10 Wp, 11 bp
    const float* values = (const float*)d_in[2];
    const int*   edges  = (const int*)d_in[3];
    const float* Wv     = (const float*)d_in[8];
    const float* bv     = (const float*)d_in[9];
    const float* Wp     = (const float*)d_in[10];
    const float* bp     = (const float*)d_in[11];

    float* out  = (float*)d_out;
    float* attn = out;                                  // [B,S,E]
    float* A1   = out + (size_t)BATCH * S * E;          // [B,S,S]
    float* A2   = A1 + (size_t)BATCH * S * S;           // [B,S,S]

    // A-region zeroing: rocclr fill is at the 1.073 GB write floor
    // (~170 us); our custom fills measured no better (R1/R2).
    (void)hipMemsetAsync(A1, 0, (size_t)2 * BATCH * S * S * sizeof(float),
                         stream);

    init_attn_kernel<<<ATTN_N4 / 256, 256, 0, stream>>>(attn, bp);

    // Single fused scatter: leader test, group dedupe, two matvecs, A ones.
    scatter3_kernel<<<TOTAL_EDGES, 128, 0, stream>>>(
        edges, values, Wv, bv, Wp, bp, attn, A1, A2);
}

// Round 7
// 1079.385 us; speedup vs baseline: 1.4459x; 1.0023x over previous
//
#include <hip/hip_runtime.h>

// Problem constants: WIDTH=64 -> S=4096, E=128, B=8, 512 edges/batch.
#define WIDTH 64
#define S 4096
#define E 128
#define BATCH 8
#define EDGES_PER_B 512
#define TOTAL_EDGES (BATCH * EDGES_PER_B)
#define ROWS_PER_BLOCK 8                // 512 blocks/batch x 8 rows = S

typedef float vfloat4 __attribute__((ext_vector_type(4)));

// Session ledger (R0-R6): timed window = harness poison fills (~863 us
// fixed) + A-memset (~170 us, at the 1.073 GB write floor) + controllable
// residual. R6 residual ~49 us; this round removes the separate bp-init
// pass (+launch) by giving every block dual duty.
//
// Block g (128 threads):
//  DUTY 1 (all blocks): write A1/A2 ones for edge g (duplicates: same
//    addr, same value -> benign race).
//  DUTY 2 (all blocks): for its 8-row range of the batch, write
//    attn[row,:] = bp for rows with NO incident edge.
//  DUTY 3 (leader blocks: edge g is the first occurrence of src in the
//    batch): attn[b,src,:] = ((sum over unique dsts of values[b,dst,:])
//    @ Wv + cnt*bv) @ Wp + bp  — one contiguous 512 B store.
// Every attn row has exactly one writer: range-block if no incident edge,
// unique leader block otherwise.
__global__ __launch_bounds__(128) void scatter4_kernel(
    const int* __restrict__ edges, const float* __restrict__ values,
    const float* __restrict__ Wv, const float* __restrict__ bv,
    const float* __restrict__ Wp, const float* __restrict__ bp,
    float* __restrict__ attn, float* __restrict__ A1,
    float* __restrict__ A2) {
    const int g = blockIdx.x;            // edge index, 0..4095
    const int b = g >> 9;                // / EDGES_PER_B
    const int ib = g & (EDGES_PER_B - 1);
    const int4 e = reinterpret_cast<const int4*>(edges)[g];
    const int src = e.y * WIDTH + e.x;   // node = y*WIDTH + x
    const int dst = e.w * WIDTH + e.z;
    const int aidx = (b * S + src) * S + dst;
    if (threadIdx.x == 0) A1[aidx] = 1.0f;
    if (threadIdx.x == 1) A2[aidx] = 1.0f;

    __shared__ int s_src[EDGES_PER_B];
    __shared__ int s_dst[EDGES_PER_B];
    __shared__ int gidx[EDGES_PER_B];    // compacted same-src edge indices
    __shared__ int owned[ROWS_PER_BLOCK];
    __shared__ int nl;                   // not-leader flag
    __shared__ int gcnt;
    __shared__ float vsum[E];
    __shared__ float hv[E];
    const int t = threadIdx.x;
    if (t == 0) { nl = 0; gcnt = 0; }
    if (t < ROWS_PER_BLOCK) owned[t] = 0;
    const int4* eb = reinterpret_cast<const int4*>(edges) + b * EDGES_PER_B;
#pragma unroll
    for (int r = 0; r < EDGES_PER_B / 128; ++r) {
        const int i = t + r * 128;
        int4 ee = eb[i];                 // 65 KB/batch -> L2-hot
        s_src[i] = ee.y * WIDTH + ee.x;
        s_dst[i] = ee.w * WIDTH + ee.z;
    }
    __syncthreads();

    // Parallel: leader test + same-src group collection + row-range
    // ownership marking. 4 edges per thread.
    const int rbase = ib * ROWS_PER_BLOCK;   // this block's row range
#pragma unroll
    for (int r = 0; r < EDGES_PER_B / 128; ++r) {
        const int j = t + r * 128;
        const int sj = s_src[j];
        if (sj == src) {
            if (j < ib) nl = 1;          // earlier same-src edge exists
            gidx[atomicAdd(&gcnt, 1)] = j;   // LDS atomic, unordered
        }
        const int rr = sj - rbase;
        if ((unsigned)rr < ROWS_PER_BLOCK) owned[rr] = 1;  // benign race
    }
    __syncthreads();

    // DUTY 2: bp rows for un-owned rows in this block's range.
    const float bpt = bp[t];
#pragma unroll
    for (int r = 0; r < ROWS_PER_BLOCK; ++r) {
        if (!owned[r])
            attn[(size_t)(b * S + rbase + r) * E + t] = bpt;
    }

    if (nl) return;                      // uniform (LDS value post-sync)

    // DUTY 3 (leaders): gather unique-dst values rows (group size gsz is
    // uniform, typically 1-8). Pair-unique(m): no group member with
    // smaller original index and the same dst.
    const int gsz = gcnt;
    float vs = 0.0f, fcnt = 0.0f;
    for (int m = 0; m < gsz; ++m) {
        const int jm = gidx[m];
        const int dm = s_dst[jm];
        bool uq = true;
        for (int mm = 0; mm < gsz; ++mm) {
            const int jmm = gidx[mm];
            if (jmm < jm && s_dst[jmm] == dm) uq = false;
        }
        if (uq) {
            vs += values[(size_t)(b * S + dm) * E + t];
            fcnt += 1.0f;
        }
    }
    vsum[t] = vs;
    __syncthreads();

    // hv = vsum @ Wv + cnt*bv (bias scales by unique-dst count).
    float acc = fcnt * bv[t];
#pragma unroll 8
    for (int k = 0; k < E; ++k) acc += vsum[k] * Wv[k * E + t];
    hv[t] = acc;
    __syncthreads();

    // attn row = hv @ Wp + bp, one contiguous 512 B store.
    float p = bpt;
#pragma unroll 8
    for (int k = 0; k < E; ++k) p += hv[k] * Wp[k * E + t];
    attn[(size_t)(b * S + src) * E + t] = p;
}

extern "C" void kernel_launch(void* const* d_in, const int* in_sizes, int n_in,
                              void* d_out, int out_size, void* d_ws,
                              size_t ws_size, hipStream_t stream) {
    // 0 queries, 1 keys, 2 values, 3 oracle_edges, 4 Wq, 5 bq, 6 Wk, 7 bk,
    // 8 Wv, 9 bv, 10 Wp, 11 bp
    const float* values = (const float*)d_in[2];
    const int*   edges  = (const int*)d_in[3];
    const float* Wv     = (const float*)d_in[8];
    const float* bv     = (const float*)d_in[9];
    const float* Wp     = (const float*)d_in[10];
    const float* bp     = (const float*)d_in[11];

    float* out  = (float*)d_out;
    float* attn = out;                                  // [B,S,E]
    float* A1   = out + (size_t)BATCH * S * E;          // [B,S,S]
    float* A2   = A1 + (size_t)BATCH * S * S;           // [B,S,S]

    // A-region zeroing: rocclr fill is at the 1.073 GB write floor
    // (~170 us); our custom fills measured no better (R1/R2).
    (void)hipMemsetAsync(A1, 0, (size_t)2 * BATCH * S * S * sizeof(float),
                         stream);

    // Single fused kernel: bp rows + leader rows + A ones. Two dispatches
    // total for the whole problem.
    scatter4_kernel<<<TOTAL_EDGES, 128, 0, stream>>>(
        edges, values, Wv, bv, Wp, bp, attn, A1, A2);
}